// Round 7
// baseline (392.958 us; speedup 1.0000x reference)
//
#include <hip/hip_runtime.h>

#define HH 1024
#define WW 1024
#define TW 64          // output tile width
#define TH 32          // output tile height
#define SUS 92         // sU stride floats (44 rows, 76 cols used)
#define SLS 76         // sL stride floats (40 rows, 72 cols used + 4 junk)
#define SGS 76         // sG stride floats (36 rows, 68 cols used + junk) overlays sL
#define DTC (0.1f/3.0f)

__global__ __launch_bounds__(256, 4) void pde_layer(
    const float* __restrict__ Uin,
    const float* __restrict__ K1,
    const float* __restrict__ K2,
    const float* __restrict__ Aw,
    float* __restrict__ Uout)
{
    __shared__ __align__(16) float sU[44 * SUS];   // 16192 B (intact: identity + recompute)
    __shared__ __align__(16) float sL[40 * SLS];   // 12160 B (lam0, lam1, then grad)
    float* const sG = sL;

    const int tid = threadIdx.x;
    const int bx = blockIdx.x * TW;
    const int by = blockIdx.y * TH;
    const size_t plane = (size_t)blockIdx.z * (size_t)(HH * WW);
    const float* __restrict__ Ub = Uin + plane;
    float* __restrict__ Ob = Uout + plane;

    // uniform weights -> SGPRs
    float w0[25], w1[25], aw[25];
    #pragma unroll
    for (int t = 0; t < 25; ++t) { w0[t] = K1[t]; w1[t] = K1[25 + t]; aw[t] = Aw[t]; }
    const float k2a = K2[0], k2b = K2[1];

    // ---- stage 0: load U tile 44r x 76c ----
    const bool xedge = (bx == 0) || (bx + TW == WW);
    if (!xedge) {
        for (int it = tid; it < 44 * 19; it += 256) {
            int r = it / 19, q = it - r * 19;
            int gr = (by + r - 6) & (HH - 1);
            const float* row = Ub + ((size_t)gr << 10);
            int c = bx - 6 + (q << 2);
            float2 a = *(const float2*)(row + c);
            float2 b = *(const float2*)(row + c + 2);
            float4 v; v.x = a.x; v.y = a.y; v.z = b.x; v.w = b.y;
            *(float4*)&sU[r * SUS + (q << 2)] = v;
        }
    } else {
        for (int it = tid; it < 44 * 19; it += 256) {
            int r = it / 19, q = it - r * 19;
            int gr = (by + r - 6) & (HH - 1);
            const float* row = Ub + ((size_t)gr << 10);
            int c = bx - 6 + (q << 2);
            float4 v;
            v.x = row[(c + 0) & (WW - 1)];
            v.y = row[(c + 1) & (WW - 1)];
            v.z = row[(c + 2) & (WW - 1)];
            v.w = row[(c + 3) & (WW - 1)];
            *(float4*)&sU[r * SUS + (q << 2)] = v;
        }
    }
    __syncthreads();

    // item decomposition: 4 rows x 8 cols per item
    const int rg1 = tid / 9, cg1 = tid - (tid / 9) * 9;   // s1/s1': 10x9 = 90 items (40r x 72c)
    const bool s1 = (tid < 90);
    const bool s2 = (tid < 81);                            // s2: 9x9 = 81 items (36r x 72c)
    const int rg3 = tid >> 3, cg3 = tid & 7;               // s3: 8x8 = 64 items (32r x 64c)
    const bool s3 = (tid < 64);

    float gacc[4][8];   // grad accumulator, parked across s1' (32 regs)

    // ---- stage 1 (ch0): lam0 = relu(conv5(U,w0))*k2a ----
    if (s1) {
        const float* src = &sU[(rg1 * 4) * SUS + cg1 * 8];
        float acc[4][8] = {};
        #pragma unroll
        for (int ri = 0; ri < 8; ++ri) {
            float u[12];
            *(float4*)&u[0] = *(const float4*)&src[ri * SUS];
            *(float4*)&u[4] = *(const float4*)&src[ri * SUS + 4];
            *(float4*)&u[8] = *(const float4*)&src[ri * SUS + 8];
            #pragma unroll
            for (int k = 0; k < 4; ++k) {
                const int i = ri - k;
                if (i >= 0 && i < 5) {
                    #pragma unroll
                    for (int j = 0; j < 5; ++j) {
                        const float a = w0[i * 5 + j];
                        #pragma unroll
                        for (int cq = 0; cq < 8; ++cq)
                            acc[k][cq] = fmaf(u[cq + j], a, acc[k][cq]);
                    }
                }
            }
        }
        #pragma unroll
        for (int k = 0; k < 4; ++k) {
            float4 o0, o1;
            o0.x = fmaxf(acc[k][0], 0.f) * k2a;
            o0.y = fmaxf(acc[k][1], 0.f) * k2a;
            o0.z = fmaxf(acc[k][2], 0.f) * k2a;
            o0.w = fmaxf(acc[k][3], 0.f) * k2a;
            o1.x = fmaxf(acc[k][4], 0.f) * k2a;
            o1.y = fmaxf(acc[k][5], 0.f) * k2a;
            o1.z = fmaxf(acc[k][6], 0.f) * k2a;
            o1.w = fmaxf(acc[k][7], 0.f) * k2a;
            *(float4*)&sL[(rg1 * 4 + k) * SLS + cg1 * 8]     = o0;
            *(float4*)&sL[(rg1 * 4 + k) * SLS + cg1 * 8 + 4] = o1;
        }
    }
    __syncthreads();

    // ---- stage 2a: gacc = conv5(lam0, flip(w0)) ----
    if (s2) {
        #pragma unroll
        for (int k = 0; k < 4; ++k)
            #pragma unroll
            for (int c = 0; c < 8; ++c) gacc[k][c] = 0.f;
        const float* p = &sL[(rg1 * 4) * SLS + cg1 * 8];
        #pragma unroll
        for (int ri = 0; ri < 8; ++ri) {
            float u[12];
            *(float4*)&u[0] = *(const float4*)&p[ri * SLS];
            *(float4*)&u[4] = *(const float4*)&p[ri * SLS + 4];
            *(float4*)&u[8] = *(const float4*)&p[ri * SLS + 8];
            #pragma unroll
            for (int k = 0; k < 4; ++k) {
                const int i = ri - k;
                if (i >= 0 && i < 5) {
                    #pragma unroll
                    for (int j = 0; j < 5; ++j) {
                        const float a = w0[24 - (i * 5 + j)];   // flipped
                        #pragma unroll
                        for (int cq = 0; cq < 8; ++cq)
                            gacc[k][cq] = fmaf(u[cq + j], a, gacc[k][cq]);
                    }
                }
            }
        }
    }
    __syncthreads();

    // ---- stage 1' (ch1): recompute from intact sU; lam1 = relu(conv5(U,w1))*k2b ----
    if (s1) {
        const float* src = &sU[(rg1 * 4) * SUS + cg1 * 8];
        float acc[4][8] = {};
        #pragma unroll
        for (int ri = 0; ri < 8; ++ri) {
            float u[12];
            *(float4*)&u[0] = *(const float4*)&src[ri * SUS];
            *(float4*)&u[4] = *(const float4*)&src[ri * SUS + 4];
            *(float4*)&u[8] = *(const float4*)&src[ri * SUS + 8];
            #pragma unroll
            for (int k = 0; k < 4; ++k) {
                const int i = ri - k;
                if (i >= 0 && i < 5) {
                    #pragma unroll
                    for (int j = 0; j < 5; ++j) {
                        const float a = w1[i * 5 + j];
                        #pragma unroll
                        for (int cq = 0; cq < 8; ++cq)
                            acc[k][cq] = fmaf(u[cq + j], a, acc[k][cq]);
                    }
                }
            }
        }
        #pragma unroll
        for (int k = 0; k < 4; ++k) {
            float4 o0, o1;
            o0.x = fmaxf(acc[k][0], 0.f) * k2b;
            o0.y = fmaxf(acc[k][1], 0.f) * k2b;
            o0.z = fmaxf(acc[k][2], 0.f) * k2b;
            o0.w = fmaxf(acc[k][3], 0.f) * k2b;
            o1.x = fmaxf(acc[k][4], 0.f) * k2b;
            o1.y = fmaxf(acc[k][5], 0.f) * k2b;
            o1.z = fmaxf(acc[k][6], 0.f) * k2b;
            o1.w = fmaxf(acc[k][7], 0.f) * k2b;
            *(float4*)&sL[(rg1 * 4 + k) * SLS + cg1 * 8]     = o0;
            *(float4*)&sL[(rg1 * 4 + k) * SLS + cg1 * 8 + 4] = o1;
        }
    }
    __syncthreads();

    // ---- stage 2b: gacc += conv5(lam1, flip(w1)) ----
    if (s2) {
        const float* p = &sL[(rg1 * 4) * SLS + cg1 * 8];
        #pragma unroll
        for (int ri = 0; ri < 8; ++ri) {
            float u[12];
            *(float4*)&u[0] = *(const float4*)&p[ri * SLS];
            *(float4*)&u[4] = *(const float4*)&p[ri * SLS + 4];
            *(float4*)&u[8] = *(const float4*)&p[ri * SLS + 8];
            #pragma unroll
            for (int k = 0; k < 4; ++k) {
                const int i = ri - k;
                if (i >= 0 && i < 5) {
                    #pragma unroll
                    for (int j = 0; j < 5; ++j) {
                        const float a = w1[24 - (i * 5 + j)];   // flipped
                        #pragma unroll
                        for (int cq = 0; cq < 8; ++cq)
                            gacc[k][cq] = fmaf(u[cq + j], a, gacc[k][cq]);
                    }
                }
            }
        }
    }
    __syncthreads();

    // ---- write grad -> sG (overlays sL; all sL reads complete) ----
    if (s2) {
        #pragma unroll
        for (int k = 0; k < 4; ++k) {
            float4 o0, o1;
            o0.x = gacc[k][0]; o0.y = gacc[k][1]; o0.z = gacc[k][2]; o0.w = gacc[k][3];
            o1.x = gacc[k][4]; o1.y = gacc[k][5]; o1.z = gacc[k][6]; o1.w = gacc[k][7];
            *(float4*)&sG[(rg1 * 4 + k) * SGS + cg1 * 8]     = o0;
            *(float4*)&sG[(rg1 * 4 + k) * SGS + cg1 * 8 + 4] = o1;
        }
    }
    __syncthreads();

    // ---- stage 3: out = U + dt/3 * conv5(grad, A); identity from sU ----
    if (s3) {
        const float* p = &sG[(rg3 * 4) * SGS + cg3 * 8];
        float acc[4][8] = {};
        #pragma unroll
        for (int ri = 0; ri < 8; ++ri) {
            float u[12];
            *(float4*)&u[0] = *(const float4*)&p[ri * SGS];
            *(float4*)&u[4] = *(const float4*)&p[ri * SGS + 4];
            *(float4*)&u[8] = *(const float4*)&p[ri * SGS + 8];
            #pragma unroll
            for (int k = 0; k < 4; ++k) {
                const int i = ri - k;
                if (i >= 0 && i < 5) {
                    #pragma unroll
                    for (int j = 0; j < 5; ++j) {
                        const float a = aw[i * 5 + j];
                        #pragma unroll
                        for (int cq = 0; cq < 8; ++cq)
                            acc[k][cq] = fmaf(u[cq + j], a, acc[k][cq]);
                    }
                }
            }
        }
        #pragma unroll
        for (int k = 0; k < 4; ++k) {
            const int r = rg3 * 4 + k;
            const float* idr = &sU[(r + 6) * SUS + cg3 * 8 + 6];
            float2 i0 = *(const float2*)&idr[0];
            float2 i1 = *(const float2*)&idr[2];
            float2 i2 = *(const float2*)&idr[4];
            float2 i3 = *(const float2*)&idr[6];
            float4 o0, o1;
            o0.x = i0.x + DTC * acc[k][0];
            o0.y = i0.y + DTC * acc[k][1];
            o0.z = i1.x + DTC * acc[k][2];
            o0.w = i1.y + DTC * acc[k][3];
            o1.x = i2.x + DTC * acc[k][4];
            o1.y = i2.y + DTC * acc[k][5];
            o1.z = i3.x + DTC * acc[k][6];
            o1.w = i3.y + DTC * acc[k][7];
            float* orow = &Ob[((size_t)(by + r) << 10) + bx + cg3 * 8];
            *(float4*)&orow[0] = o0;
            *(float4*)&orow[4] = o1;
        }
    }
}

extern "C" void kernel_launch(void* const* d_in, const int* in_sizes, int n_in,
                              void* d_out, int out_size, void* d_ws, size_t ws_size,
                              hipStream_t stream) {
    const float* U  = (const float*)d_in[0];
    const float* K1 = (const float*)d_in[1];
    const float* K2 = (const float*)d_in[2];
    const float* Aw = (const float*)d_in[3];
    float* out = (float*)d_out;
    float* ws  = (float*)d_ws;

    const int B = in_sizes[0] / (HH * WW);   // 16
    dim3 grid(WW / TW, HH / TH, B);

    // 3 Euler layers; ping-pong in -> out -> ws -> out
    pde_layer<<<grid, 256, 0, stream>>>(U,   K1, K2, Aw, out);
    pde_layer<<<grid, 256, 0, stream>>>(out, K1, K2, Aw, ws);
    pde_layer<<<grid, 256, 0, stream>>>(ws,  K1, K2, Aw, out);
}

// Round 8
// 308.035 us; speedup vs baseline: 1.2757x; 1.2757x over previous
//
#include <hip/hip_runtime.h>

#define HH 1024
#define WW 1024
#define BH 64              // output rows per block (band)
#define DTC (0.1f/3.0f)
#define NSTEP 80           // 64 out rows + 15 pipeline depth + 1 pad

// Full-width row pipeline. Each thread owns one column. Per step s:
//   D(s-1) published U row d = by-6+s-1 ; A(s) halo-completes it and adds its
//   5 vertical-tap contributions to the 5 pending lam partial sums, emitting
//   lam row d-2. Same cascade for grad (B) and vec (C). One barrier per step.
// Out row o(s) = by + s - 15, valid s in [15,78].
__global__ __launch_bounds__(1024, 4) void pde_band(
    const float* __restrict__ Uin,
    const float* __restrict__ K1,
    const float* __restrict__ K2,
    const float* __restrict__ Aw,
    float* __restrict__ Uout)
{
    __shared__ float shU[2][WW];
    __shared__ float shL[2][2][WW];
    __shared__ float shG[2][WW];

    const int c  = threadIdx.x;
    const int by = blockIdx.x * BH;
    const size_t plane = (size_t)blockIdx.y * (size_t)(HH * WW);
    const float* __restrict__ Ub = Uin + plane;
    float* __restrict__ Ob = Uout + plane;

    // uniform weights (compiler scalarizes -> SGPRs, proven rounds 1-7)
    float w0[25], w1[25], aw[25];
#pragma unroll
    for (int t = 0; t < 25; ++t) { w0[t] = K1[t]; w1[t] = K1[25 + t]; aw[t] = Aw[t]; }
    const float k2a = K2[0], k2b = K2[1];

    // wrapped halo columns (byte-cheap: reused every step as ds_read addrs)
    const int cm2 = (c - 2) & (WW - 1), cm1 = (c - 1) & (WW - 1);
    const int cp1 = (c + 1) & (WW - 1), cp2 = (c + 2) & (WW - 1);

    // partial-sum rings (static-indexed via unroll)
    float pL0[5] = {0,0,0,0,0}, pL1[5] = {0,0,0,0,0};
    float pG[5]  = {0,0,0,0,0}, pV[5]  = {0,0,0,0,0};
    float uPrev = 0.f, lPrev0 = 0.f, lPrev1 = 0.f, gPrev = 0.f;

    // zero the slot read at s=0 (determinism; values provably unused anyway)
    shU[1][c] = 0.f; shL[1][0][c] = 0.f; shL[1][1][c] = 0.f; shG[1][c] = 0.f;

    // prefetch for step 0
    float uNew = Ub[(size_t)((unsigned)(by - 6)  & (HH - 1)) * WW + c];
    float idv  = Ub[(size_t)((unsigned)(by - 15) & (HH - 1)) * WW + c];

    for (int sb = 0; sb < NSTEP / 10; ++sb) {
#pragma unroll
      for (int p = 0; p < 10; ++p) {
        const int s   = sb * 10 + p;
        const int p5  = p % 5;      // literal after unroll
        const int wsl = p & 1;      // literal after unroll
        const int rsl = wsl ^ 1;
        __syncthreads();

        // ---- A: halo-complete U row, update lam partials, emit lam ----
        float uf[5];
        uf[0] = shU[rsl][cm2]; uf[1] = shU[rsl][cm1]; uf[2] = uPrev;
        uf[3] = shU[rsl][cp1]; uf[4] = shU[rsl][cp2];
#pragma unroll
        for (int t = 0; t < 5; ++t) {
          const int sl = (p5 + t) % 5;
#pragma unroll
          for (int j = 0; j < 5; ++j) {
            pL0[sl] = fmaf(uf[j], w0[(4 - t) * 5 + j], pL0[sl]);
            pL1[sl] = fmaf(uf[j], w1[(4 - t) * 5 + j], pL1[sl]);
          }
        }
        const float l0 = fmaxf(pL0[p5], 0.f) * k2a;
        const float l1 = fmaxf(pL1[p5], 0.f) * k2b;
        pL0[p5] = 0.f; pL1[p5] = 0.f;
        shL[wsl][0][c] = l0; shL[wsl][1][c] = l1;

        // ---- B: halo-complete lam row, update grad partials, emit grad ----
        float lf0[5], lf1[5];
        lf0[0] = shL[rsl][0][cm2]; lf0[1] = shL[rsl][0][cm1]; lf0[2] = lPrev0;
        lf0[3] = shL[rsl][0][cp1]; lf0[4] = shL[rsl][0][cp2];
        lf1[0] = shL[rsl][1][cm2]; lf1[1] = shL[rsl][1][cm1]; lf1[2] = lPrev1;
        lf1[3] = shL[rsl][1][cp1]; lf1[4] = shL[rsl][1][cp2];
#pragma unroll
        for (int t = 0; t < 5; ++t) {
          const int sl = (p5 + t) % 5;
#pragma unroll
          for (int j = 0; j < 5; ++j) {
            // conv_transpose: weight K1[ch][4-i][4-j] with i = 4-t  ->  w[t*5 + 4-j]
            pG[sl] = fmaf(lf0[j], w0[t * 5 + 4 - j], pG[sl]);
            pG[sl] = fmaf(lf1[j], w1[t * 5 + 4 - j], pG[sl]);
          }
        }
        const float g = pG[p5]; pG[p5] = 0.f;
        shG[wsl][c] = g;

        // ---- C: halo-complete grad row, update vec partials, emit out ----
        float gf[5];
        gf[0] = shG[rsl][cm2]; gf[1] = shG[rsl][cm1]; gf[2] = gPrev;
        gf[3] = shG[rsl][cp1]; gf[4] = shG[rsl][cp2];
#pragma unroll
        for (int t = 0; t < 5; ++t) {
          const int sl = (p5 + t) % 5;
#pragma unroll
          for (int j = 0; j < 5; ++j)
            pV[sl] = fmaf(gf[j], aw[(4 - t) * 5 + j], pV[sl]);
        }
        const float v = pV[p5]; pV[p5] = 0.f;
        if (s >= 15 && s <= 78)
          Ob[(size_t)(by + s - 15) * WW + c] = idv + DTC * v;

        // ---- D: publish new U row, rotate centers, prefetch next ----
        shU[wsl][c] = uNew;
        uPrev = uNew; lPrev0 = l0; lPrev1 = l1; gPrev = g;
        uNew = Ub[(size_t)((unsigned)(by - 5 + s)  & (HH - 1)) * WW + c];
        idv  = Ub[(size_t)((unsigned)(by - 14 + s) & (HH - 1)) * WW + c];
      }
    }
}

extern "C" void kernel_launch(void* const* d_in, const int* in_sizes, int n_in,
                              void* d_out, int out_size, void* d_ws, size_t ws_size,
                              hipStream_t stream) {
    const float* U  = (const float*)d_in[0];
    const float* K1 = (const float*)d_in[1];
    const float* K2 = (const float*)d_in[2];
    const float* Aw = (const float*)d_in[3];
    float* out = (float*)d_out;
    float* ws  = (float*)d_ws;

    const int B = in_sizes[0] / (HH * WW);   // 16
    dim3 grid(HH / BH, B);                   // 16 bands x 16 images = 256 blocks (1/CU)

    // 3 Euler layers; ping-pong in -> out -> ws -> out
    pde_band<<<grid, 1024, 0, stream>>>(U,   K1, K2, Aw, out);
    pde_band<<<grid, 1024, 0, stream>>>(out, K1, K2, Aw, ws);
    pde_band<<<grid, 1024, 0, stream>>>(ws,  K1, K2, Aw, out);
}